// Round 1
// baseline (234.984 us; speedup 1.0000x reference)
//
#include <hip/hip_runtime.h>
#include <hip/hip_bf16.h>
#include <math.h>

#define IN_CH 512
#define HID   1024
#define NH    16
#define HD    64
#define BSZ   1024
#define KVB   (NH * (2 * HD + 1))   // 2064
#define LN_EPS 1e-5f

// C[m][n] = sum_k A[m][k] * B[n][k] + bias[n]   (C = A @ B^T + bias)
// A: M x K row-major, B: N x K row-major. K % 16 == 0, M % 64 == 0, N % 4 == 0.
__global__ __launch_bounds__(256) void gemm_tn(const float* __restrict__ A,
                                               const float* __restrict__ B,
                                               const float* __restrict__ bias,
                                               float* __restrict__ C,
                                               int M, int N, int K) {
    const int BM = 64, BN = 64, BK = 16, PAD = 68;
    __shared__ float As[BK][PAD];
    __shared__ float Bs[BK][PAD];

    const int t   = threadIdx.x;
    const int m0  = blockIdx.y * BM;
    const int n0  = blockIdx.x * BN;
    const int row = t >> 2;            // 0..63
    const int kq  = (t & 3) * 4;       // 0,4,8,12
    const int tx  = t & 15;            // n micro
    const int ty  = t >> 4;            // m micro

    float acc[4][4] = {};

    for (int k0 = 0; k0 < K; k0 += BK) {
        float4 a4 = *(const float4*)(A + (size_t)(m0 + row) * K + k0 + kq);
        float4 b4 = make_float4(0.f, 0.f, 0.f, 0.f);
        if (n0 + row < N)
            b4 = *(const float4*)(B + (size_t)(n0 + row) * K + k0 + kq);

        __syncthreads();
        As[kq + 0][row] = a4.x; As[kq + 1][row] = a4.y;
        As[kq + 2][row] = a4.z; As[kq + 3][row] = a4.w;
        Bs[kq + 0][row] = b4.x; Bs[kq + 1][row] = b4.y;
        Bs[kq + 2][row] = b4.z; Bs[kq + 3][row] = b4.w;
        __syncthreads();

        #pragma unroll
        for (int k = 0; k < BK; ++k) {
            float4 av = *(const float4*)&As[k][ty * 4];
            float4 bv = *(const float4*)&Bs[k][tx * 4];
            float a[4] = {av.x, av.y, av.z, av.w};
            float b[4] = {bv.x, bv.y, bv.z, bv.w};
            #pragma unroll
            for (int i = 0; i < 4; ++i)
                #pragma unroll
                for (int j = 0; j < 4; ++j)
                    acc[i][j] = fmaf(a[i], b[j], acc[i][j]);
        }
    }

    const int n = n0 + tx * 4;
    if (n < N) {   // N % 4 == 0 and n % 4 == 0 -> whole quad in-bounds
        float4 bb = *(const float4*)(bias + n);
        #pragma unroll
        for (int i = 0; i < 4; ++i) {
            const int m = m0 + ty * 4 + i;
            float4 o = make_float4(acc[i][0] + bb.x, acc[i][1] + bb.y,
                                   acc[i][2] + bb.z, acc[i][3] + bb.w);
            *(float4*)(C + (size_t)m * N + n) = o;
        }
    }
}

// In-place row LayerNorm: one block per row of h (1024 cols, 256 threads x float4)
__global__ __launch_bounds__(256) void ln_rows(float* __restrict__ h,
                                               const float* __restrict__ gamma,
                                               const float* __restrict__ beta) {
    const int row = blockIdx.x;
    const int t   = threadIdx.x;
    float* hr = h + (size_t)row * HID;

    float4 v = *(const float4*)(hr + t * 4);
    float s  = v.x + v.y + v.z + v.w;
    float sq = v.x * v.x + v.y * v.y + v.z * v.z + v.w * v.w;

    #pragma unroll
    for (int off = 1; off < 64; off <<= 1) {
        s  += __shfl_xor(s, off);
        sq += __shfl_xor(sq, off);
    }
    __shared__ float red[8];
    const int wid = t >> 6;
    if ((t & 63) == 0) { red[wid] = s; red[4 + wid] = sq; }
    __syncthreads();
    s  = red[0] + red[1] + red[2] + red[3];
    sq = red[4] + red[5] + red[6] + red[7];

    const float mu  = s * (1.f / HID);
    const float var = sq * (1.f / HID) - mu * mu;
    const float inv = rsqrtf(var + LN_EPS);

    float4 g  = *(const float4*)(gamma + t * 4);
    float4 be = *(const float4*)(beta + t * 4);
    v.x = (v.x - mu) * inv * g.x + be.x;
    v.y = (v.y - mu) * inv * g.y + be.y;
    v.z = (v.z - mu) * inv * g.z + be.z;
    v.w = (v.w - mu) * inv * g.w + be.w;
    *(float4*)(hr + t * 4) = v;
}

// One wave per (b, head) pair. Reads out2 slice (129 f32) + W block (64x64),
// writes dW block (64x64). All W/dW accesses are coalesced float4.
__global__ __launch_bounds__(256) void oja_tail(const float* __restrict__ out2,
                                                const float* __restrict__ W,
                                                float* __restrict__ dW) {
    const int lane = threadIdx.x & 63;
    const int wid  = threadIdx.x >> 6;
    const int pair = blockIdx.x * 4 + wid;      // 0..16383 == b*16 + head
    const int b    = pair >> 4;
    const int head = pair & 15;

    const float* orow = out2 + (size_t)b * KVB + head * (2 * HD + 1);

    const float kin   = orow[lane];
    const float vfull = tanhf(orow[64 + lane]);
    float t3 = 0.f;
    if (lane == 0) t3 = orow[128];
    const float lrl = __shfl(t3, 0);
    const float lr  = 1.f / (1.f + expf(-lrl));

    const int g   = lane >> 4;     // 0..3  (i-group)
    const int c16 = lane & 15;     // j-quad index

    const float* wbh = W + (size_t)pair * (HD * HD);

    float rem[4] = {0.f, 0.f, 0.f, 0.f};
    #pragma unroll
    for (int tt = 0; tt < 16; ++tt) {
        const int i = 4 * tt + g;
        const float vsi = __shfl(vfull, i);
        float4 w4 = *(const float4*)(wbh + i * 64 + c16 * 4);
        rem[0] = fmaf(w4.x, vsi, rem[0]);
        rem[1] = fmaf(w4.y, vsi, rem[1]);
        rem[2] = fmaf(w4.z, vsi, rem[2]);
        rem[3] = fmaf(w4.w, vsi, rem[3]);
    }
    #pragma unroll
    for (int q = 0; q < 4; ++q) {
        rem[q] += __shfl_xor(rem[q], 16);
        rem[q] += __shfl_xor(rem[q], 32);
    }

    // logits for j = c16*4 + q  (replicated across the 4 g-groups)
    float L[4];
    #pragma unroll
    for (int q = 0; q < 4; ++q)
        L[q] = __shfl(kin, 4 * c16 + q) - rem[q];

    float mx = fmaxf(fmaxf(L[0], L[1]), fmaxf(L[2], L[3]));
    #pragma unroll
    for (int off = 1; off < 16; off <<= 1)
        mx = fmaxf(mx, __shfl_xor(mx, off));

    float e[4], ssum = 0.f;
    #pragma unroll
    for (int q = 0; q < 4; ++q) { e[q] = expf(L[q] - mx); ssum += e[q]; }
    #pragma unroll
    for (int off = 1; off < 16; off <<= 1)
        ssum += __shfl_xor(ssum, off);

    const float scale = lr / ssum;
    float ks[4];
    #pragma unroll
    for (int q = 0; q < 4; ++q) ks[q] = e[q] * scale;

    float* obh = dW + (size_t)pair * (HD * HD);
    #pragma unroll
    for (int tt = 0; tt < 16; ++tt) {
        const int i = 4 * tt + g;
        const float vsi = __shfl(vfull, i);
        float4 o = make_float4(vsi * ks[0], vsi * ks[1], vsi * ks[2], vsi * ks[3]);
        *(float4*)(obh + i * 64 + c16 * 4) = o;
    }
}

extern "C" void kernel_launch(void* const* d_in, const int* in_sizes, int n_in,
                              void* d_out, int out_size, void* d_ws, size_t ws_size,
                              hipStream_t stream) {
    const float* x     = (const float*)d_in[0];
    const float* W     = (const float*)d_in[1];
    const float* w_in  = (const float*)d_in[2];
    const float* b_in  = (const float*)d_in[3];
    const float* gamma = (const float*)d_in[4];
    const float* beta  = (const float*)d_in[5];
    const float* w_kvb = (const float*)d_in[6];
    const float* b_kvb = (const float*)d_in[7];
    float* dW = (float*)d_out;

    float* h    = (float*)d_ws;                 // 1024*1024 f32
    float* out2 = h + (size_t)BSZ * HID;        // 1024*2064 f32

    // h = x @ w_in^T + b_in
    gemm_tn<<<dim3(HID / 64, BSZ / 64), 256, 0, stream>>>(x, w_in, b_in, h,
                                                          BSZ, HID, IN_CH);
    // LayerNorm rows of h (in place)
    ln_rows<<<BSZ, 256, 0, stream>>>(h, gamma, beta);
    // out2 = h @ w_kvb^T + b_kvb
    gemm_tn<<<dim3((KVB + 63) / 64, BSZ / 64), 256, 0, stream>>>(h, w_kvb, b_kvb,
                                                                 out2, BSZ, KVB, HID);
    // tail: tanh/sigmoid, ks_remove, softmax, outer product
    oja_tail<<<(BSZ * NH) / 4, 256, 0, stream>>>(out2, W, dW);
}

// Round 2
// 156.985 us; speedup vs baseline: 1.4969x; 1.4969x over previous
//
#include <hip/hip_runtime.h>
#include <hip/hip_bf16.h>
#include <math.h>

#define IN_CH 512
#define HID   1024
#define NH    16
#define HD    64
#define BSZ   1024
#define KVB   2064
#define NPAD  2112
#define LN_EPS 1e-5f

typedef short bf16x8 __attribute__((ext_vector_type(8)));
typedef float f32x4  __attribute__((ext_vector_type(4)));
typedef unsigned short u16;

__device__ inline u16 f2bf(float f) {                 // RNE bf16 bits
    unsigned u = __float_as_uint(f);
    unsigned r = u + 0x7FFFu + ((u >> 16) & 1u);
    return (u16)(r >> 16);
}
__device__ inline float bf2f(u16 u) {
    return __uint_as_float(((unsigned)u) << 16);
}

__device__ inline void gload16(const void* g, void* l) {
    __builtin_amdgcn_global_load_lds(
        (const __attribute__((address_space(1))) unsigned int*)g,
        (__attribute__((address_space(3))) unsigned int*)l, 16, 0, 0);
}

// ---------------- conversion: fp32 -> bf16 hi/lo for x, w_in, w_kvb(padded) ---
#define QX (BSZ * IN_CH / 4)          // 131072
#define QW (HID * IN_CH / 4)          // 131072
#define QK (NPAD * HID / 4)           // 540672
#define QKVALID (KVB * HID / 4)       // 528384

__global__ __launch_bounds__(256) void cvt_all(const float* __restrict__ x,
                                               const float* __restrict__ w_in,
                                               const float* __restrict__ w_kvb,
                                               u16* __restrict__ xh, u16* __restrict__ xl,
                                               u16* __restrict__ wih, u16* __restrict__ wil,
                                               u16* __restrict__ wkh, u16* __restrict__ wkl) {
    long q = (long)blockIdx.x * 256 + threadIdx.x;
    const float* src; u16 *ph, *pl; long lq; bool valid = true;
    if (q < QX)            { src = x;     ph = xh;  pl = xl;  lq = q; }
    else if (q < QX + QW)  { src = w_in;  ph = wih; pl = wil; lq = q - QX; }
    else                   { src = w_kvb; ph = wkh; pl = wkl; lq = q - QX - QW;
                             valid = lq < QKVALID; }
    float4 v = valid ? ((const float4*)src)[lq] : make_float4(0.f, 0.f, 0.f, 0.f);
    float f[4] = {v.x, v.y, v.z, v.w};
    ushort4 hh, ll;
    u16 hb[4], lb[4];
    #pragma unroll
    for (int j = 0; j < 4; ++j) {
        hb[j] = f2bf(f[j]);
        lb[j] = f2bf(f[j] - bf2f(hb[j]));
    }
    hh.x = hb[0]; hh.y = hb[1]; hh.z = hb[2]; hh.w = hb[3];
    ll.x = lb[0]; ll.y = lb[1]; ll.z = lb[2]; ll.w = lb[3];
    ((ushort4*)ph)[lq] = hh;
    ((ushort4*)pl)[lq] = ll;
}

// ---------------- split-precision MFMA GEMM:  C = A @ B^T + bias -------------
// A: M x K fp32 given as (Ah,Al) bf16;  B: N x K as (Bh,Bl).  256 thr = 4 waves (2x2).
template<int BM, int BN>
__global__ __launch_bounds__(256) void gemm_split(const u16* __restrict__ Ah_g,
                                                  const u16* __restrict__ Al_g,
                                                  const u16* __restrict__ Bh_g,
                                                  const u16* __restrict__ Bl_g,
                                                  const float* __restrict__ bias,
                                                  float* __restrict__ C,
                                                  int M, int N, int K, int ldc) {
    constexpr int WM = BM / 2, WN = BN / 2, MF = WM / 16, NF = WN / 16;
    __shared__ __align__(16) u16 Ah[2][BM][32];
    __shared__ __align__(16) u16 Al[2][BM][32];
    __shared__ __align__(16) u16 Bh[2][BN][32];
    __shared__ __align__(16) u16 Bl[2][BN][32];

    const int t = threadIdx.x, lane = t & 63, wid = t >> 6;
    const int wm = wid >> 1, wn = wid & 1;
    const int m0 = blockIdx.y * BM, n0 = blockIdx.x * BN;

    f32x4 acc[MF][NF] = {};

    auto stage = [&](int buf, int k0) {
        #pragma unroll
        for (int s = 0; s < BM / 64; ++s) {
            int row = s * 64 + wid * 16 + (lane >> 2);
            int seg = (lane & 3) ^ (row & 3);               // pre-swizzled source
            size_t go = (size_t)(m0 + row) * K + k0 + seg * 8;
            gload16(Ah_g + go, &Ah[buf][s * 64 + wid * 16][0]);
            gload16(Al_g + go, &Al[buf][s * 64 + wid * 16][0]);
        }
        #pragma unroll
        for (int s = 0; s < BN / 64; ++s) {
            int row = s * 64 + wid * 16 + (lane >> 2);
            int seg = (lane & 3) ^ (row & 3);
            size_t go = (size_t)(n0 + row) * K + k0 + seg * 8;
            gload16(Bh_g + go, &Bh[buf][s * 64 + wid * 16][0]);
            gload16(Bl_g + go, &Bl[buf][s * 64 + wid * 16][0]);
        }
    };

    const int KT = K / 32;
    stage(0, 0);
    __syncthreads();
    int buf = 0;
    for (int kt = 0; kt < KT; ++kt) {
        if (kt + 1 < KT) stage(buf ^ 1, (kt + 1) * 32);

        bf16x8 ah[MF], al[MF], bh[NF], bl[NF];
        #pragma unroll
        for (int mf = 0; mf < MF; ++mf) {
            int r = wm * WM + mf * 16 + (lane & 15);
            int c = (lane >> 4) ^ (r & 3);                  // swizzled read
            ah[mf] = *(const bf16x8*)&Ah[buf][r][c * 8];
            al[mf] = *(const bf16x8*)&Al[buf][r][c * 8];
        }
        #pragma unroll
        for (int nf = 0; nf < NF; ++nf) {
            int r = wn * WN + nf * 16 + (lane & 15);
            int c = (lane >> 4) ^ (r & 3);
            bh[nf] = *(const bf16x8*)&Bh[buf][r][c * 8];
            bl[nf] = *(const bf16x8*)&Bl[buf][r][c * 8];
        }
        #pragma unroll
        for (int mf = 0; mf < MF; ++mf)
            #pragma unroll
            for (int nf = 0; nf < NF; ++nf) {
                acc[mf][nf] = __builtin_amdgcn_mfma_f32_16x16x32_bf16(ah[mf], bh[nf], acc[mf][nf], 0, 0, 0);
                acc[mf][nf] = __builtin_amdgcn_mfma_f32_16x16x32_bf16(ah[mf], bl[nf], acc[mf][nf], 0, 0, 0);
                acc[mf][nf] = __builtin_amdgcn_mfma_f32_16x16x32_bf16(al[mf], bh[nf], acc[mf][nf], 0, 0, 0);
            }
        __syncthreads();
        buf ^= 1;
    }

    #pragma unroll
    for (int mf = 0; mf < MF; ++mf)
        #pragma unroll
        for (int nf = 0; nf < NF; ++nf) {
            int col = n0 + wn * WN + nf * 16 + (lane & 15);
            if (col < N) {
                float bb = bias[col];
                #pragma unroll
                for (int r = 0; r < 4; ++r) {
                    int row = m0 + wm * WM + mf * 16 + ((lane >> 4) << 2) + r;
                    C[(size_t)row * ldc + col] = acc[mf][nf][r] + bb;
                }
            }
        }
}

// ---------------- LayerNorm rows of h -> bf16 hi/lo ---------------------------
__global__ __launch_bounds__(256) void ln_rows(const float* __restrict__ h,
                                               const float* __restrict__ gamma,
                                               const float* __restrict__ beta,
                                               u16* __restrict__ hh,
                                               u16* __restrict__ hl) {
    const int row = blockIdx.x;
    const int t   = threadIdx.x;
    const float* hr = h + (size_t)row * HID;

    float4 v = *(const float4*)(hr + t * 4);
    float s  = v.x + v.y + v.z + v.w;
    float sq = v.x * v.x + v.y * v.y + v.z * v.z + v.w * v.w;

    #pragma unroll
    for (int off = 1; off < 64; off <<= 1) {
        s  += __shfl_xor(s, off);
        sq += __shfl_xor(sq, off);
    }
    __shared__ float red[8];
    const int wid = t >> 6;
    if ((t & 63) == 0) { red[wid] = s; red[4 + wid] = sq; }
    __syncthreads();
    s  = red[0] + red[1] + red[2] + red[3];
    sq = red[4] + red[5] + red[6] + red[7];

    const float mu  = s * (1.f / HID);
    const float var = sq * (1.f / HID) - mu * mu;
    const float inv = rsqrtf(var + LN_EPS);

    float4 g  = *(const float4*)(gamma + t * 4);
    float4 be = *(const float4*)(beta + t * 4);
    float o[4];
    o[0] = (v.x - mu) * inv * g.x + be.x;
    o[1] = (v.y - mu) * inv * g.y + be.y;
    o[2] = (v.z - mu) * inv * g.z + be.z;
    o[3] = (v.w - mu) * inv * g.w + be.w;

    ushort4 uh, ul;
    u16 hb[4], lb[4];
    #pragma unroll
    for (int j = 0; j < 4; ++j) {
        hb[j] = f2bf(o[j]);
        lb[j] = f2bf(o[j] - bf2f(hb[j]));
    }
    uh.x = hb[0]; uh.y = hb[1]; uh.z = hb[2]; uh.w = hb[3];
    ul.x = lb[0]; ul.y = lb[1]; ul.z = lb[2]; ul.w = lb[3];
    ((ushort4*)(hh + (size_t)row * HID))[t] = uh;
    ((ushort4*)(hl + (size_t)row * HID))[t] = ul;
}

// ---------------- tail: one wave per (b, head) --------------------------------
__global__ __launch_bounds__(256) void oja_tail(const float* __restrict__ out2,
                                                const float* __restrict__ W,
                                                float* __restrict__ dW) {
    const int lane = threadIdx.x & 63;
    const int wid  = threadIdx.x >> 6;
    const int pair = blockIdx.x * 4 + wid;      // b*16 + head
    const int b    = pair >> 4;
    const int head = pair & 15;

    const float* orow = out2 + (size_t)b * KVB + head * (2 * HD + 1);

    const float kin   = orow[lane];
    const float vfull = tanhf(orow[64 + lane]);
    float t3 = 0.f;
    if (lane == 0) t3 = orow[128];
    const float lrl = __shfl(t3, 0);
    const float lr  = 1.f / (1.f + expf(-lrl));

    const int g   = lane >> 4;
    const int c16 = lane & 15;

    const float* wbh = W + (size_t)pair * (HD * HD);

    float rem[4] = {0.f, 0.f, 0.f, 0.f};
    #pragma unroll
    for (int tt = 0; tt < 16; ++tt) {
        const int i = 4 * tt + g;
        const float vsi = __shfl(vfull, i);
        float4 w4 = *(const float4*)(wbh + i * 64 + c16 * 4);
        rem[0] = fmaf(w4.x, vsi, rem[0]);
        rem[1] = fmaf(w4.y, vsi, rem[1]);
        rem[2] = fmaf(w4.z, vsi, rem[2]);
        rem[3] = fmaf(w4.w, vsi, rem[3]);
    }
    #pragma unroll
    for (int q = 0; q < 4; ++q) {
        rem[q] += __shfl_xor(rem[q], 16);
        rem[q] += __shfl_xor(rem[q], 32);
    }

    float L[4];
    #pragma unroll
    for (int q = 0; q < 4; ++q)
        L[q] = __shfl(kin, 4 * c16 + q) - rem[q];

    float mx = fmaxf(fmaxf(L[0], L[1]), fmaxf(L[2], L[3]));
    #pragma unroll
    for (int off = 1; off < 16; off <<= 1)
        mx = fmaxf(mx, __shfl_xor(mx, off));

    float e[4], ssum = 0.f;
    #pragma unroll
    for (int q = 0; q < 4; ++q) { e[q] = expf(L[q] - mx); ssum += e[q]; }
    #pragma unroll
    for (int off = 1; off < 16; off <<= 1)
        ssum += __shfl_xor(ssum, off);

    const float scale = lr / ssum;
    float ks[4];
    #pragma unroll
    for (int q = 0; q < 4; ++q) ks[q] = e[q] * scale;

    float* obh = dW + (size_t)pair * (HD * HD);
    #pragma unroll
    for (int tt = 0; tt < 16; ++tt) {
        const int i = 4 * tt + g;
        const float vsi = __shfl(vfull, i);
        float4 o = make_float4(vsi * ks[0], vsi * ks[1], vsi * ks[2], vsi * ks[3]);
        *(float4*)(obh + i * 64 + c16 * 4) = o;
    }
}

extern "C" void kernel_launch(void* const* d_in, const int* in_sizes, int n_in,
                              void* d_out, int out_size, void* d_ws, size_t ws_size,
                              hipStream_t stream) {
    const float* x     = (const float*)d_in[0];
    const float* W     = (const float*)d_in[1];
    const float* w_in  = (const float*)d_in[2];
    const float* b_in  = (const float*)d_in[3];
    const float* gamma = (const float*)d_in[4];
    const float* beta  = (const float*)d_in[5];
    const float* w_kvb = (const float*)d_in[6];
    const float* b_kvb = (const float*)d_in[7];
    float* dW = (float*)d_out;

    char* p = (char*)d_ws;
    auto carve = [&](size_t bytes) { char* r = p; p += (bytes + 255) & ~(size_t)255; return r; };
    float* h    = (float*)carve((size_t)BSZ * HID * 4);
    float* out2 = (float*)carve((size_t)BSZ * KVB * 4);
    u16* xh  = (u16*)carve((size_t)BSZ * IN_CH * 2);
    u16* xl  = (u16*)carve((size_t)BSZ * IN_CH * 2);
    u16* wih = (u16*)carve((size_t)HID * IN_CH * 2);
    u16* wil = (u16*)carve((size_t)HID * IN_CH * 2);
    u16* hh  = (u16*)carve((size_t)BSZ * HID * 2);
    u16* hl  = (u16*)carve((size_t)BSZ * HID * 2);
    u16* wkh = (u16*)carve((size_t)NPAD * HID * 2);
    u16* wkl = (u16*)carve((size_t)NPAD * HID * 2);

    const int totQ = QX + QW + QK;                 // 802816 quads
    cvt_all<<<totQ / 256, 256, 0, stream>>>(x, w_in, w_kvb, xh, xl, wih, wil, wkh, wkl);

    // h = x @ w_in^T + b_in     (M=1024, N=1024, K=512)
    gemm_split<64, 64><<<dim3(HID / 64, BSZ / 64), 256, 0, stream>>>(
        xh, xl, wih, wil, b_in, h, BSZ, HID, IN_CH, HID);

    // LayerNorm + hi/lo convert
    ln_rows<<<BSZ, 256, 0, stream>>>(h, gamma, beta, hh, hl);

    // out2 = h @ w_kvb^T + b_kvb  (M=1024, N=2064 (padded 2112), K=1024)
    gemm_split<128, 64><<<dim3(NPAD / 64, BSZ / 128), 256, 0, stream>>>(
        hh, hl, wkh, wkl, b_kvb, out2, BSZ, KVB, HID, KVB);

    // tail
    oja_tail<<<(BSZ * NH) / 4, 256, 0, stream>>>(out2, W, dW);
}